// Round 3
// baseline (1909.925 us; speedup 1.0000x reference)
//
#include <hip/hip_runtime.h>

// out[E,64] = segment_sum(feat[nbr[:,1]], nbr[:,0]) @ K[64,64] + bias
// R3: coarse bucket partition (dst>>7, 128 dsts/bucket) -> per-bucket LDS
// accumulation (ds_add_f32, padded rows) -> readlane/fmac transform (VALU,
// not LDS pipe). Packed pair word: src | (dst&127)<<19  (needs E <= 2^19).

#define FD 64
#define BKT 128
#define NREP 8

// ---------- partition pipeline ----------

__global__ __launch_bounds__(256) void k_bhist(const int* __restrict__ nbr,
                                               int* __restrict__ cnt, int P) {
    int p = blockIdx.x * 256 + threadIdx.x;
    if (p < P) {
        int b = nbr[2 * p] >> 7;
        atomicAdd(&cnt[b * NREP + (blockIdx.x & (NREP - 1))], 1);
    }
}

// single block exclusive scan over M0 counters -> base[] and cur[] (copies)
__global__ __launch_bounds__(1024) void k_scan(const int* __restrict__ cnt,
                                               int* __restrict__ base,
                                               int* __restrict__ cur,
                                               int M0, int P) {
    __shared__ int ts[1024];
    const int t = threadIdx.x;
    const int CH = (M0 + 1023) / 1024;
    const int lo = t * CH, hi = (lo + CH < M0) ? lo + CH : M0;
    int s = 0;
    for (int i = lo; i < hi; ++i) s += cnt[i];
    ts[t] = s;
    __syncthreads();
    for (int off = 1; off < 1024; off <<= 1) {
        int v = (t >= off) ? ts[t - off] : 0;
        __syncthreads();
        ts[t] += v;
        __syncthreads();
    }
    int run = ts[t] - s;  // exclusive prefix of this chunk
    for (int i = lo; i < hi; ++i) {
        int c = cnt[i];
        base[i] = run;
        cur[i] = run;
        run += c;
    }
    if (t == 0) base[M0] = P;
}

__global__ __launch_bounds__(256) void k_part(const int* __restrict__ nbr,
                                              int* __restrict__ cur,
                                              unsigned* __restrict__ pk, int P) {
    int p = blockIdx.x * 256 + threadIdx.x;
    if (p < P) {
        int dst = nbr[2 * p + 0];
        int src = nbr[2 * p + 1];
        int b = dst >> 7;
        int pos = atomicAdd(&cur[b * NREP + (blockIdx.x & (NREP - 1))], 1);
        pk[pos] = (unsigned)src | ((unsigned)(dst & (BKT - 1)) << 19);
    }
}

// ---------- fused aggregate + transform: one block per bucket ----------

__global__ __launch_bounds__(256) void k_bagg(const float* __restrict__ feat,
                                              const int* __restrict__ base,
                                              const unsigned* __restrict__ pk,
                                              const float* __restrict__ Kmat,
                                              const float* __restrict__ bias,
                                              float* __restrict__ out, int E) {
    __shared__ float acc[BKT * (FD + 1)];
    const int tid = threadIdx.x, lane = tid & 63, wid = tid >> 6;
    const int b = blockIdx.x;

    for (int i = tid; i < BKT * (FD + 1); i += 256) acc[i] = 0.f;

    float kcol[FD];
#pragma unroll
    for (int d = 0; d < FD; ++d) kcol[d] = Kmat[d * FD + lane];
    const float bv = bias[lane];
    __syncthreads();

    const int beg = base[b * NREP], end = base[(b + 1) * NREP];
    // each wave takes batches of 64 pairs: coalesced pair load, then scalar
    // broadcast via readlane; per pair: 1 global_load_dword + 1 ds_add_f32
    for (int i = beg + wid * 64; i < end; i += 256) {
        int myp = i + lane;
        unsigned v = (myp < end) ? pk[myp] : 0xFFFFFFFFu;
#pragma unroll
        for (int j = 0; j < 64; ++j) {
            unsigned pv = (unsigned)__builtin_amdgcn_readlane((int)v, j);
            if (pv != 0xFFFFFFFFu) {  // wave-uniform branch
                unsigned src = pv & 0x7FFFFu;
                unsigned ld = pv >> 19;
                float f = feat[(size_t)src * FD + lane];
                atomicAdd(&acc[ld * (FD + 1) + lane], f);
            }
        }
    }
    __syncthreads();

    // transform: 32 rows per wave; row values broadcast via readlane (VALU),
    // K column in 64 VGPRs (lane = output unit u)
    const int e0 = b * BKT;
    for (int k = 0; k < 32; ++k) {
        int r = wid * 32 + k;
        int e = e0 + r;
        if (e >= E) break;  // wave-uniform
        float x = acc[r * (FD + 1) + lane];
        float o0 = bv, o1 = 0.f, o2 = 0.f, o3 = 0.f;
#pragma unroll
        for (int d = 0; d < FD; d += 4) {
            o0 += __uint_as_float(__builtin_amdgcn_readlane(__float_as_uint(x), d + 0)) * kcol[d + 0];
            o1 += __uint_as_float(__builtin_amdgcn_readlane(__float_as_uint(x), d + 1)) * kcol[d + 1];
            o2 += __uint_as_float(__builtin_amdgcn_readlane(__float_as_uint(x), d + 2)) * kcol[d + 2];
            o3 += __uint_as_float(__builtin_amdgcn_readlane(__float_as_uint(x), d + 3)) * kcol[d + 3];
        }
        out[(size_t)e * FD + lane] = (o0 + o1) + (o2 + o3);
    }
}

// ---------- fallback (round-1 path) ----------

__global__ __launch_bounds__(256) void ea_scatter(const float* __restrict__ feat,
                                                  const int* __restrict__ nbr,
                                                  float* __restrict__ agg, int P) {
    const int lane = threadIdx.x & 63;
    const int pair = __builtin_amdgcn_readfirstlane(
        (int)blockIdx.x * 4 + ((int)threadIdx.x >> 6));
    if (pair < P) {
        const int dst = nbr[2 * pair + 0];
        const int src = nbr[2 * pair + 1];
        atomicAdd(&agg[(size_t)dst * FD + lane], feat[(size_t)src * FD + lane]);
    }
}

__global__ __launch_bounds__(256) void ea_transform(float* __restrict__ io,
                                                    const float* __restrict__ Kmat,
                                                    const float* __restrict__ bias,
                                                    int E) {
    const int lane = threadIdx.x & 63;
    float kcol[FD];
#pragma unroll
    for (int d = 0; d < FD; ++d) kcol[d] = Kmat[d * FD + lane];
    const float b = bias[lane];
    const int wv = __builtin_amdgcn_readfirstlane(
        (int)blockIdx.x * 4 + ((int)threadIdx.x >> 6));
    const int nw = (int)gridDim.x * 4;
    for (int e = wv; e < E; e += nw) {
        const float* __restrict__ row = io + (size_t)e * FD;
        float acc = b;
#pragma unroll
        for (int d = 0; d < FD; ++d) acc += row[d] * kcol[d];
        io[(size_t)e * FD + lane] = acc;
    }
}

// ---------- launcher ----------

extern "C" void kernel_launch(void* const* d_in, const int* in_sizes, int n_in,
                              void* d_out, int out_size, void* d_ws, size_t ws_size,
                              hipStream_t stream) {
    const float* feat = (const float*)d_in[0];
    const int* nbr = (const int*)d_in[1];
    const float* Kmat = (const float*)d_in[2];
    const float* bias = (const float*)d_in[3];
    float* out = (float*)d_out;

    const int E = in_sizes[0] / FD;  // 500000
    const int P = in_sizes[1] / 2;   // 4000000

    const int B = (E + BKT - 1) / BKT;  // buckets
    const int M0 = B * NREP;            // replicated counters
    const size_t need = ((size_t)M0 * 3 + 1 + (size_t)P) * sizeof(int);

    if (ws_size >= need && E <= (1 << 19)) {
        int* cnt = (int*)d_ws;          // M0
        int* cur = cnt + M0;            // M0
        int* base = cur + M0;           // M0 + 1
        unsigned* pk = (unsigned*)(base + M0 + 1);  // P

        hipMemsetAsync(cnt, 0, (size_t)M0 * sizeof(int), stream);
        k_bhist<<<(P + 255) / 256, 256, 0, stream>>>(nbr, cnt, P);
        k_scan<<<1, 1024, 0, stream>>>(cnt, base, cur, M0, P);
        k_part<<<(P + 255) / 256, 256, 0, stream>>>(nbr, cur, pk, P);
        k_bagg<<<B, 256, 0, stream>>>(feat, base, pk, Kmat, bias, out, E);
    } else {
        hipMemsetAsync(d_out, 0, (size_t)out_size * sizeof(float), stream);
        ea_scatter<<<(P + 3) / 4, 256, 0, stream>>>(feat, nbr, out, P);
        ea_transform<<<2048, 256, 0, stream>>>(out, Kmat, bias, E);
    }
}